// Round 2
// baseline (953.591 us; speedup 1.0000x reference)
//
#include <hip/hip_runtime.h>
#include <stdint.h>

// ---------------------------------------------------------------------------
// FrameSoftAttention: out = softmax((q Wq^T)(k Wk^T)^T / 16) (v Wv^T)
// B=128, I=J=1024, D_IN=D_INNER=256, fp32 in/out, bf16 MFMA compute.
// v3 = v2 + fix: proj epilogue for mat==2 (V) must TRANSPOSE in LDS
//      (ldst[n][m]) before the coalesced store into vt[e][j] — v2 dropped
//      this and stored vh untransposed (absmax 6.6e-2).
// v2: T3 minimum-2-phase pipeline everywhere (double-buffered staging
//     halves, stage-next-before-compute, single vmcnt(0)+s_barrier per
//     chunk); proj reads X once (full-N tile); W pre-converted to bf16.
// ---------------------------------------------------------------------------

typedef __attribute__((ext_vector_type(4))) float f32x4;
typedef __attribute__((ext_vector_type(8))) short bf16x8;
typedef __attribute__((ext_vector_type(4))) uint32_t u32x4;
typedef __attribute__((ext_vector_type(4))) short s16x4;

#define MFMA(a, b, c) __builtin_amdgcn_mfma_f32_16x16x32_bf16(a, b, c, 0, 0, 0)

typedef const __attribute__((address_space(1))) uint32_t* gas1_t;
typedef __attribute__((address_space(3))) uint32_t* las3_t;

__device__ __forceinline__ void async16(const void* g, void* l) {
  // 16B direct global->LDS; lands at wave-uniform base + lane*16.
  __builtin_amdgcn_global_load_lds((gas1_t)g, (las3_t)l, 16, 0, 0);
}

__device__ __forceinline__ short f2bf_rne(float f) {
  uint32_t u = __builtin_bit_cast(uint32_t, f);
  u += 0x7FFFu + ((u >> 16) & 1u);
  return (short)(u >> 16);
}

// two fp32 -> packed bf16 pair by truncation (cheap; bias inside 2% budget)
__device__ __forceinline__ uint32_t pack2(float lo, float hi) {
  uint32_t a = __builtin_bit_cast(uint32_t, lo);
  uint32_t b = __builtin_bit_cast(uint32_t, hi);
  return (a >> 16) | (b & 0xFFFF0000u);
}

// Pipeline barrier: drain OWN in-flight global_load_lds, then block barrier.
// Raw s_barrier (no lgkm drain: ds_read results are consumed by MFMAs before
// this point, so reads are already complete). sched_barrier pins ordering.
__device__ __forceinline__ void wait_barrier() {
  __builtin_amdgcn_sched_barrier(0);
  asm volatile("s_waitcnt vmcnt(0)" ::: "memory");
  __builtin_amdgcn_s_barrier();
  __builtin_amdgcn_sched_barrier(0);
}

// ---------------------------------------------------------------------------
// W fp32 [256][256] -> bf16 row-major, all three mats. 768KB read, runs ~5us.
// ---------------------------------------------------------------------------
__global__ __launch_bounds__(256)
void wconv_kernel(const float* __restrict__ wq, const float* __restrict__ wk,
                  const float* __restrict__ wv, short* __restrict__ wbf) {
  const int mat = blockIdx.y;
  const float* w = (mat == 0) ? wq : (mat == 1) ? wk : wv;
  const int i = (blockIdx.x * 256 + threadIdx.x) * 4;
  f32x4 v = *(const f32x4*)(w + i);
  s16x4 o = {f2bf_rne(v.x), f2bf_rne(v.y), f2bf_rne(v.z), f2bf_rne(v.w)};
  *(s16x4*)(wbf + (size_t)mat * 65536 + i) = o;
}

// ---------------------------------------------------------------------------
// Projection: Y[m,e] = sum_d X[m,d] * W[e,d]; M=131072, N=K=256.
// One block = 128 rows x FULL 256 cols (X read once from HBM).
// 4 waves at 64x128, acc[4][8]. K-loop: 8 chunks of 32, pipelined:
// half h (32KB) = X chunk 128x32 fp32 (16KB) | W chunk 256x32 bf16 (16KB).
// ---------------------------------------------------------------------------
__global__ __launch_bounds__(256, 2)
void proj_kernel(const float* __restrict__ xq, const float* __restrict__ xk,
                 const float* __restrict__ xv, const short* __restrict__ wbf,
                 short* __restrict__ qh, short* __restrict__ kh,
                 short* __restrict__ vt) {
  __shared__ __align__(16) char smem[65536];   // 2 x 32KB halves
  short* ldst = (short*)smem;                  // epilogue alias [128][136]

  const int mat = blockIdx.y;
  const float* x = (mat == 0) ? xq : (mat == 1) ? xk : xv;
  const short* w = wbf + (size_t)mat * 65536;

  const int tile_m = blockIdx.x * 128;
  const int t = threadIdx.x;
  const int lane = t & 63, wid = t >> 6;
  const int wm = (wid & 1) * 64, wn = (wid >> 1) * 128;
  const int lr = lane & 15, lq = lane >> 4;

  f32x4 acc[4][8];
#pragma unroll
  for (int i = 0; i < 4; ++i)
#pragma unroll
    for (int j = 0; j < 8; ++j) acc[i][j] = (f32x4)0.0f;

  // stage chunk kk into half h: 8 async16 per thread (4 X + 4 W)
  auto STAGE = [&](int kk, int h) {
    char* base = smem + h * 32768;
    const int k0 = kk * 32;
#pragma unroll
    for (int c = 0; c < 4; ++c) {
      int s = c * 256 + t;
      // X slot(r,c8) = (r>>4)*128 + c8*16 + (r&15), c8 in 0..7 (fp32x4 units)
      int rx = ((s >> 7) << 4) | (s & 15);
      int cx = (s >> 4) & 7;
      async16(x + (size_t)(tile_m + rx) * 256 + k0 + cx * 4, base + s * 16);
      // W slot(r,c8) = (r>>4)*64 + c8*16 + (r&15), c8 in 0..3 (bf16x8 units)
      int rw = ((s >> 6) << 4) | (s & 15);
      int cw = (s >> 4) & 3;
      async16(w + (size_t)rw * 256 + k0 + cw * 8, base + 16384 + s * 16);
    }
  };

  STAGE(0, 0);
  wait_barrier();
  int cur = 0;
  for (int kk = 0; kk < 8; ++kk) {
    if (kk < 7) STAGE(kk + 1, cur ^ 1);   // loads fly under this chunk's work
    const f32x4* x4 = (const f32x4*)(smem + cur * 32768);
    const f32x4* w4 = (const f32x4*)(smem + cur * 32768 + 16384);
    bf16x8 af[4], bf[8];
#pragma unroll
    for (int mi = 0; mi < 4; ++mi) {
      int row = wm + mi * 16 + lr;
      int sl = ((row >> 4) << 7) + (lq << 5) + (row & 15);
      f32x4 lo = x4[sl], hi = x4[sl + 16];
      u32x4 pk = {pack2(lo.x, lo.y), pack2(lo.z, lo.w), pack2(hi.x, hi.y),
                  pack2(hi.z, hi.w)};
      af[mi] = __builtin_bit_cast(bf16x8, pk);
    }
#pragma unroll
    for (int ni = 0; ni < 8; ++ni) {
      int col = wn + ni * 16 + lr;
      bf[ni] = __builtin_bit_cast(
          bf16x8, w4[((col >> 4) << 6) + (lq << 4) + (col & 15)]);
    }
    __builtin_amdgcn_s_setprio(1);
#pragma unroll
    for (int mi = 0; mi < 4; ++mi)
#pragma unroll
      for (int ni = 0; ni < 8; ++ni)
        acc[mi][ni] = MFMA(af[mi], bf[ni], acc[mi][ni]);
    __builtin_amdgcn_s_setprio(0);
    wait_barrier();
    cur ^= 1;
  }

  // Epilogue: two 128-col passes through LDS -> coalesced 16B stores.
  // mat==2 (V): transpose in LDS (ldst[n][m]) so LDS rows become e-rows,
  // matching the vt[e][j] store layout.  <-- v3 fix (v2 dropped this)
  const float scale = (mat == 0) ? 0.0625f : 1.0f;
  const int bb = tile_m >> 10, j0 = tile_m & 1023;
#pragma unroll
  for (int p = 0; p < 2; ++p) {
    if ((wid >> 1) == p) {
#pragma unroll
      for (int mi = 0; mi < 4; ++mi)
#pragma unroll
        for (int ni = 0; ni < 8; ++ni)
#pragma unroll
          for (int r = 0; r < 4; ++r) {
            int m = wm + mi * 16 + lq * 4 + r;   // C/D: row=(lane>>4)*4+reg
            int n = ni * 16 + lr;                //      col=lane&15 (local)
            short bv = f2bf_rne(acc[mi][ni][r] * scale);
            if (mat < 2) ldst[m * 136 + n] = bv;
            else         ldst[n * 136 + m] = bv;
          }
    }
    __syncthreads();
#pragma unroll
    for (int q = 0; q < 8; ++q) {
      int idx = q * 256 + t;
      int row = idx >> 4;
      int col8 = (idx & 15) * 8;
      bf16x8 vdat = *(const bf16x8*)(ldst + row * 136 + col8);
      short* dst;
      if (mat < 2) {
        short* o = (mat == 0) ? qh : kh;
        dst = o + (size_t)(tile_m + row) * 256 + p * 128 + col8;
      } else {
        dst = vt + ((size_t)(bb * 256 + p * 128 + row)) * 1024 + j0 + col8;
      }
      *(bf16x8*)dst = vdat;
    }
    __syncthreads();
  }
}

// ---------------------------------------------------------------------------
// Attention: one block per (batch, 128-row q tile). grid=(128, 8) so all
// q-tiles of batch b hash to XCD b%8 (kh/vt L2 reuse).
// Unit ring per j-tile: 8 QK chunks + 4 V chunks, each 16KB, alternating
// between two staging halves; next unit's loads issued before this unit's
// MFMAs, one vmcnt(0)+s_barrier per unit (13 barriers/jt vs 25 before,
// all with latency overlapped).
// ---------------------------------------------------------------------------
__global__ __launch_bounds__(256, 2)
void attn_kernel(const short* __restrict__ qh, const short* __restrict__ kh,
                 const short* __restrict__ vt, float* __restrict__ out) {
  __shared__ __align__(16) char smem[32768 + 34816];
  short* ldsS = (short*)smem;             // 2 x 16KB staging halves
  short* ldsP = (short*)(smem + 32768);   // P [128][136] bf16

  const int b = blockIdx.x;
  const int i0 = blockIdx.y * 128;
  const int t = threadIdx.x;
  const int lane = t & 63, wid = t >> 6;
  const int rg = wid >> 1, cg = wid & 1;  // wave: rows rg*64, cols cg*64/128
  const int lr = lane & 15, lq = lane >> 4;
  const size_t bq = (size_t)b * 262144;

  f32x4 oacc[4][8];
#pragma unroll
  for (int i = 0; i < 4; ++i)
#pragma unroll
    for (int j = 0; j < 8; ++j) oacc[i][j] = (f32x4)0.0f;
  float lsum[16];
#pragma unroll
  for (int i = 0; i < 16; ++i) lsum[i] = 0.0f;

  // QK unit (jt,kk) -> half h: Q chunk 8KB | K chunk 8KB; 4 loads/thread
  auto STAGE_QK = [&](int jt, int kk, int h) {
    short* base = ldsS + h * 8192;
    const int j0 = jt * 128, k0 = kk * 32;
#pragma unroll
    for (int c = 0; c < 2; ++c) {
      int s = c * 256 + t;
      int r = ((s >> 6) << 4) | (s & 15);
      int c8 = (s >> 4) & 3;
      async16(qh + bq + (size_t)(i0 + r) * 256 + k0 + c8 * 8, base + s * 8);
      async16(kh + bq + (size_t)(j0 + r) * 256 + k0 + c8 * 8,
              base + 4096 + s * 8);
    }
  };
  // V unit (jt,kc) -> half h: vt 256 d-rows x 32 j (16KB); 4 loads/thread
  auto STAGE_V = [&](int jt, int kc, int h) {
    short* base = ldsS + h * 8192;
    const int j0 = jt * 128;
#pragma unroll
    for (int c = 0; c < 4; ++c) {
      int s = c * 256 + t;
      int d = ((s >> 6) << 4) | (s & 15);
      int c8 = (s >> 4) & 3;
      async16(vt + bq + (size_t)d * 1024 + j0 + kc * 32 + c8 * 8, base + s * 8);
    }
  };

  STAGE_QK(0, 0, 0);
  wait_barrier();
  int cur = 0;

  for (int jt = 0; jt < 8; ++jt) {
    f32x4 sacc[4][4];
#pragma unroll
    for (int i = 0; i < 4; ++i)
#pragma unroll
      for (int j = 0; j < 4; ++j) sacc[i][j] = (f32x4)0.0f;

    // ---- S = Q K^T over d (8 chunks of 32), pipelined ----
    for (int kk = 0; kk < 8; ++kk) {
      if (kk < 7) STAGE_QK(jt, kk + 1, cur ^ 1);
      else        STAGE_V(jt, 0, cur ^ 1);
      const f32x4* q4 = (const f32x4*)(ldsS + cur * 8192);
      const f32x4* k4 = q4 + 512;
      bf16x8 aq[4], bk[4];
#pragma unroll
      for (int mi = 0; mi < 4; ++mi) {
        int row = rg * 64 + mi * 16 + lr;
        aq[mi] = __builtin_bit_cast(
            bf16x8, q4[((row >> 4) << 6) + (lq << 4) + (row & 15)]);
      }
#pragma unroll
      for (int ni = 0; ni < 4; ++ni) {
        int col = cg * 64 + ni * 16 + lr;
        bk[ni] = __builtin_bit_cast(
            bf16x8, k4[((col >> 4) << 6) + (lq << 4) + (col & 15)]);
      }
      __builtin_amdgcn_s_setprio(1);
#pragma unroll
      for (int mi = 0; mi < 4; ++mi)
#pragma unroll
        for (int ni = 0; ni < 4; ++ni)
          sacc[mi][ni] = MFMA(aq[mi], bk[ni], sacc[mi][ni]);
      __builtin_amdgcn_s_setprio(0);
      wait_barrier();
      cur ^= 1;
    }

    // ---- P = exp(S), row partial sums, P -> LDS (bf16) ----
    float prt[16];
#pragma unroll
    for (int i = 0; i < 16; ++i) prt[i] = 0.0f;
#pragma unroll
    for (int mi = 0; mi < 4; ++mi)
#pragma unroll
      for (int ni = 0; ni < 4; ++ni)
#pragma unroll
        for (int r = 0; r < 4; ++r) {
          float e = __expf(sacc[mi][ni][r]);
          prt[mi * 4 + r] += e;
          int m = rg * 64 + mi * 16 + lq * 4 + r;
          int jc = cg * 64 + ni * 16 + lr;
          ldsP[m * 136 + jc] = f2bf_rne(e);
        }
#pragma unroll
    for (int v = 0; v < 16; ++v) {
      float p = prt[v];
      p += __shfl_xor(p, 1, 64);
      p += __shfl_xor(p, 2, 64);
      p += __shfl_xor(p, 4, 64);
      p += __shfl_xor(p, 8, 64);
      lsum[v] += p;
    }
    __syncthreads();   // P visible to the sibling cg wave before PV reads

    // ---- O += P V (contraction over 128 keys, 4 chunks of 32), pipelined ----
    for (int kc = 0; kc < 4; ++kc) {
      if (kc < 3)      STAGE_V(jt, kc + 1, cur ^ 1);
      else if (jt < 7) STAGE_QK(jt + 1, 0, cur ^ 1);
      const f32x4* v4 = (const f32x4*)(ldsS + cur * 8192);
      const f32x4* p4 = (const f32x4*)ldsP;
      bf16x8 pf[4], vf[8];
#pragma unroll
      for (int mi = 0; mi < 4; ++mi) {
        int m = rg * 64 + mi * 16 + lr;
        pf[mi] = __builtin_bit_cast(bf16x8, p4[m * 17 + kc * 4 + lq]);
      }
#pragma unroll
      for (int ni = 0; ni < 8; ++ni) {
        int d = cg * 128 + ni * 16 + lr;
        vf[ni] = __builtin_bit_cast(
            bf16x8, v4[((d >> 4) << 6) + (lq << 4) + (d & 15)]);
      }
      __builtin_amdgcn_s_setprio(1);
#pragma unroll
      for (int mi = 0; mi < 4; ++mi)
#pragma unroll
        for (int ni = 0; ni < 8; ++ni)
          oacc[mi][ni] = MFMA(pf[mi], vf[ni], oacc[mi][ni]);
      __builtin_amdgcn_s_setprio(0);
      wait_barrier();
      cur ^= 1;
    }
  }

  // ---- epilogue: combine denominators across wave pairs, normalize ----
  float* lscr = (float*)ldsP;
  if (lr == 0) {
#pragma unroll
    for (int mi = 0; mi < 4; ++mi)
#pragma unroll
      for (int r = 0; r < 4; ++r)
        lscr[wid * 64 + mi * 16 + lq * 4 + r] = lsum[mi * 4 + r];
  }
  __syncthreads();
  float inv[16];
#pragma unroll
  for (int mi = 0; mi < 4; ++mi)
#pragma unroll
    for (int r = 0; r < 4; ++r) {
      float tot = lsum[mi * 4 + r] + lscr[(wid ^ 1) * 64 + mi * 16 + lq * 4 + r];
      inv[mi * 4 + r] = 1.0f / tot;
    }
#pragma unroll
  for (int mi = 0; mi < 4; ++mi)
#pragma unroll
    for (int ni = 0; ni < 8; ++ni)
#pragma unroll
      for (int r = 0; r < 4; ++r) {
        int i = i0 + rg * 64 + mi * 16 + lq * 4 + r;
        int d = cg * 128 + ni * 16 + lr;
        out[bq + (size_t)i * 256 + d] = oacc[mi][ni][r] * inv[mi * 4 + r];
      }
}

// ---------------------------------------------------------------------------
extern "C" void kernel_launch(void* const* d_in, const int* in_sizes, int n_in,
                              void* d_out, int out_size, void* d_ws,
                              size_t ws_size, hipStream_t stream) {
  (void)in_sizes; (void)n_in; (void)out_size; (void)ws_size;
  const float* q  = (const float*)d_in[0];
  const float* k  = (const float*)d_in[1];
  const float* v  = (const float*)d_in[2];
  const float* wq = (const float*)d_in[3];
  const float* wk = (const float*)d_in[4];
  const float* wv = (const float*)d_in[5];
  float* out = (float*)d_out;

  // ws layout: qh | kh | vt, each 128*1024*256 bf16 (67.1 MB) -> 201.3 MB
  short* qh = (short*)d_ws;
  short* kh = qh + (size_t)33554432;
  short* vt = kh + (size_t)33554432;
  // W bf16 scratch (384 KB) lives at the head of d_out; d_out is only
  // written by attn_kernel's epilogue, which runs strictly after proj.
  short* wbf = (short*)d_out;

  wconv_kernel<<<dim3(64, 3), dim3(256), 0, stream>>>(wq, wk, wv, wbf);
  proj_kernel<<<dim3(1024, 3), dim3(256), 0, stream>>>(
      q, k, v, wbf, qh, kh, vt);
  attn_kernel<<<dim3(128, 8), dim3(256), 0, stream>>>(qh, kh, vt, out);
}

// Round 3
// 905.272 us; speedup vs baseline: 1.0534x; 1.0534x over previous
//
#include <hip/hip_runtime.h>
#include <stdint.h>

// ---------------------------------------------------------------------------
// FrameSoftAttention: out = softmax((q Wq^T)(k Wk^T)^T / 16) (v Wv^T)
// B=128, I=J=1024, D_IN=D_INNER=256, fp32 in/out, bf16 MFMA compute.
// v4 = v3 minus the __launch_bounds__(256,2) min-occupancy bound: that
//      capped V+A regs at 256/wave, spilled ~30 regs -> 470MB scratch
//      writes (WRITE_SIZE 602MB vs 134MB output), attn 442->506us.
//      Plain (256) lets the allocator use ~240 regs, no spill (round-0
//      precedent), still 2 waves/SIMD.
// v3: proj mat==2 transposes in LDS before vt store.
// v2: double-buffered 2-phase pipeline (stage-next-before-compute, one
//     vmcnt(0)+s_barrier per chunk); proj reads X once; W pre-bf16.
// ---------------------------------------------------------------------------

typedef __attribute__((ext_vector_type(4))) float f32x4;
typedef __attribute__((ext_vector_type(8))) short bf16x8;
typedef __attribute__((ext_vector_type(4))) uint32_t u32x4;
typedef __attribute__((ext_vector_type(4))) short s16x4;

#define MFMA(a, b, c) __builtin_amdgcn_mfma_f32_16x16x32_bf16(a, b, c, 0, 0, 0)

typedef const __attribute__((address_space(1))) uint32_t* gas1_t;
typedef __attribute__((address_space(3))) uint32_t* las3_t;

__device__ __forceinline__ void async16(const void* g, void* l) {
  // 16B direct global->LDS; lands at wave-uniform base + lane*16.
  __builtin_amdgcn_global_load_lds((gas1_t)g, (las3_t)l, 16, 0, 0);
}

__device__ __forceinline__ short f2bf_rne(float f) {
  uint32_t u = __builtin_bit_cast(uint32_t, f);
  u += 0x7FFFu + ((u >> 16) & 1u);
  return (short)(u >> 16);
}

// two fp32 -> packed bf16 pair by truncation (cheap; bias inside 2% budget)
__device__ __forceinline__ uint32_t pack2(float lo, float hi) {
  uint32_t a = __builtin_bit_cast(uint32_t, lo);
  uint32_t b = __builtin_bit_cast(uint32_t, hi);
  return (a >> 16) | (b & 0xFFFF0000u);
}

// Pipeline barrier: drain OWN in-flight global_load_lds, then block barrier.
__device__ __forceinline__ void wait_barrier() {
  __builtin_amdgcn_sched_barrier(0);
  asm volatile("s_waitcnt vmcnt(0)" ::: "memory");
  __builtin_amdgcn_s_barrier();
  __builtin_amdgcn_sched_barrier(0);
}

// ---------------------------------------------------------------------------
// W fp32 [256][256] -> bf16 row-major, all three mats. 768KB read, ~5us.
// ---------------------------------------------------------------------------
__global__ __launch_bounds__(256)
void wconv_kernel(const float* __restrict__ wq, const float* __restrict__ wk,
                  const float* __restrict__ wv, short* __restrict__ wbf) {
  const int mat = blockIdx.y;
  const float* w = (mat == 0) ? wq : (mat == 1) ? wk : wv;
  const int i = (blockIdx.x * 256 + threadIdx.x) * 4;
  f32x4 v = *(const f32x4*)(w + i);
  s16x4 o = {f2bf_rne(v.x), f2bf_rne(v.y), f2bf_rne(v.z), f2bf_rne(v.w)};
  *(s16x4*)(wbf + (size_t)mat * 65536 + i) = o;
}

// ---------------------------------------------------------------------------
// Projection: Y[m,e] = sum_d X[m,d] * W[e,d]; M=131072, N=K=256.
// One block = 128 rows x FULL 256 cols (X read once from HBM).
// 4 waves at 64x128, acc[4][8]. K-loop: 8 chunks of 32, pipelined:
// half h (32KB) = X chunk 128x32 fp32 (16KB) | W chunk 256x32 bf16 (16KB).
// ---------------------------------------------------------------------------
__global__ __launch_bounds__(256)
void proj_kernel(const float* __restrict__ xq, const float* __restrict__ xk,
                 const float* __restrict__ xv, const short* __restrict__ wbf,
                 short* __restrict__ qh, short* __restrict__ kh,
                 short* __restrict__ vt) {
  __shared__ __align__(16) char smem[65536];   // 2 x 32KB halves
  short* ldst = (short*)smem;                  // epilogue alias [128][136]

  const int mat = blockIdx.y;
  const float* x = (mat == 0) ? xq : (mat == 1) ? xk : xv;
  const short* w = wbf + (size_t)mat * 65536;

  const int tile_m = blockIdx.x * 128;
  const int t = threadIdx.x;
  const int lane = t & 63, wid = t >> 6;
  const int wm = (wid & 1) * 64, wn = (wid >> 1) * 128;
  const int lr = lane & 15, lq = lane >> 4;

  f32x4 acc[4][8];
#pragma unroll
  for (int i = 0; i < 4; ++i)
#pragma unroll
    for (int j = 0; j < 8; ++j) acc[i][j] = (f32x4)0.0f;

  // stage chunk kk into half h: 8 async16 per thread (4 X + 4 W)
  auto STAGE = [&](int kk, int h) {
    char* base = smem + h * 32768;
    const int k0 = kk * 32;
#pragma unroll
    for (int c = 0; c < 4; ++c) {
      int s = c * 256 + t;
      // X slot(r,c8) = (r>>4)*128 + c8*16 + (r&15), c8 in 0..7 (fp32x4 units)
      int rx = ((s >> 7) << 4) | (s & 15);
      int cx = (s >> 4) & 7;
      async16(x + (size_t)(tile_m + rx) * 256 + k0 + cx * 4, base + s * 16);
      // W slot(r,c8) = (r>>4)*64 + c8*16 + (r&15), c8 in 0..3 (bf16x8 units)
      int rw = ((s >> 6) << 4) | (s & 15);
      int cw = (s >> 4) & 3;
      async16(w + (size_t)rw * 256 + k0 + cw * 8, base + 16384 + s * 16);
    }
  };

  STAGE(0, 0);
  wait_barrier();
  int cur = 0;
  for (int kk = 0; kk < 8; ++kk) {
    if (kk < 7) STAGE(kk + 1, cur ^ 1);   // loads fly under this chunk's work
    const f32x4* x4 = (const f32x4*)(smem + cur * 32768);
    const f32x4* w4 = (const f32x4*)(smem + cur * 32768 + 16384);
    bf16x8 af[4], bf[8];
#pragma unroll
    for (int mi = 0; mi < 4; ++mi) {
      int row = wm + mi * 16 + lr;
      int sl = ((row >> 4) << 7) + (lq << 5) + (row & 15);
      f32x4 lo = x4[sl], hi = x4[sl + 16];
      u32x4 pk = {pack2(lo.x, lo.y), pack2(lo.z, lo.w), pack2(hi.x, hi.y),
                  pack2(hi.z, hi.w)};
      af[mi] = __builtin_bit_cast(bf16x8, pk);
    }
#pragma unroll
    for (int ni = 0; ni < 8; ++ni) {
      int col = wn + ni * 16 + lr;
      bf[ni] = __builtin_bit_cast(
          bf16x8, w4[((col >> 4) << 6) + (lq << 4) + (col & 15)]);
    }
    __builtin_amdgcn_s_setprio(1);
#pragma unroll
    for (int mi = 0; mi < 4; ++mi)
#pragma unroll
      for (int ni = 0; ni < 8; ++ni)
        acc[mi][ni] = MFMA(af[mi], bf[ni], acc[mi][ni]);
    __builtin_amdgcn_s_setprio(0);
    wait_barrier();
    cur ^= 1;
  }

  // Epilogue: two 128-col passes through LDS -> coalesced 16B stores.
  // mat==2 (V): transpose in LDS (ldst[n][m]) so LDS rows become e-rows,
  // matching the vt[e][j] store layout.
  const float scale = (mat == 0) ? 0.0625f : 1.0f;
  const int bb = tile_m >> 10, j0 = tile_m & 1023;
#pragma unroll
  for (int p = 0; p < 2; ++p) {
    if ((wid >> 1) == p) {
#pragma unroll
      for (int mi = 0; mi < 4; ++mi)
#pragma unroll
        for (int ni = 0; ni < 8; ++ni)
#pragma unroll
          for (int r = 0; r < 4; ++r) {
            int m = wm + mi * 16 + lq * 4 + r;   // C/D: row=(lane>>4)*4+reg
            int n = ni * 16 + lr;                //      col=lane&15 (local)
            short bv = f2bf_rne(acc[mi][ni][r] * scale);
            if (mat < 2) ldst[m * 136 + n] = bv;
            else         ldst[n * 136 + m] = bv;
          }
    }
    __syncthreads();
#pragma unroll
    for (int q = 0; q < 8; ++q) {
      int idx = q * 256 + t;
      int row = idx >> 4;
      int col8 = (idx & 15) * 8;
      bf16x8 vdat = *(const bf16x8*)(ldst + row * 136 + col8);
      short* dst;
      if (mat < 2) {
        short* o = (mat == 0) ? qh : kh;
        dst = o + (size_t)(tile_m + row) * 256 + p * 128 + col8;
      } else {
        dst = vt + ((size_t)(bb * 256 + p * 128 + row)) * 1024 + j0 + col8;
      }
      *(bf16x8*)dst = vdat;
    }
    __syncthreads();
  }
}

// ---------------------------------------------------------------------------
// Attention: one block per (batch, 128-row q tile). grid=(128, 8) so all
// q-tiles of batch b hash to XCD b%8 (kh/vt L2 reuse).
// Unit ring per j-tile: 8 QK chunks + 4 V chunks, each 16KB, alternating
// between two staging halves; next unit's loads issued before this unit's
// MFMAs, one vmcnt(0)+s_barrier per unit.
// ---------------------------------------------------------------------------
__global__ __launch_bounds__(256)
void attn_kernel(const short* __restrict__ qh, const short* __restrict__ kh,
                 const short* __restrict__ vt, float* __restrict__ out) {
  __shared__ __align__(16) char smem[32768 + 34816];
  short* ldsS = (short*)smem;             // 2 x 16KB staging halves
  short* ldsP = (short*)(smem + 32768);   // P [128][136] bf16

  const int b = blockIdx.x;
  const int i0 = blockIdx.y * 128;
  const int t = threadIdx.x;
  const int lane = t & 63, wid = t >> 6;
  const int rg = wid >> 1, cg = wid & 1;  // wave: rows rg*64, cols cg*64/128
  const int lr = lane & 15, lq = lane >> 4;
  const size_t bq = (size_t)b * 262144;

  f32x4 oacc[4][8];
#pragma unroll
  for (int i = 0; i < 4; ++i)
#pragma unroll
    for (int j = 0; j < 8; ++j) oacc[i][j] = (f32x4)0.0f;
  float lsum[16];
#pragma unroll
  for (int i = 0; i < 16; ++i) lsum[i] = 0.0f;

  // QK unit (jt,kk) -> half h: Q chunk 8KB | K chunk 8KB; 4 loads/thread
  auto STAGE_QK = [&](int jt, int kk, int h) {
    short* base = ldsS + h * 8192;
    const int j0 = jt * 128, k0 = kk * 32;
#pragma unroll
    for (int c = 0; c < 2; ++c) {
      int s = c * 256 + t;
      int r = ((s >> 6) << 4) | (s & 15);
      int c8 = (s >> 4) & 3;
      async16(qh + bq + (size_t)(i0 + r) * 256 + k0 + c8 * 8, base + s * 8);
      async16(kh + bq + (size_t)(j0 + r) * 256 + k0 + c8 * 8,
              base + 4096 + s * 8);
    }
  };
  // V unit (jt,kc) -> half h: vt 256 d-rows x 32 j (16KB); 4 loads/thread
  auto STAGE_V = [&](int jt, int kc, int h) {
    short* base = ldsS + h * 8192;
    const int j0 = jt * 128;
#pragma unroll
    for (int c = 0; c < 4; ++c) {
      int s = c * 256 + t;
      int d = ((s >> 6) << 4) | (s & 15);
      int c8 = (s >> 4) & 3;
      async16(vt + bq + (size_t)d * 1024 + j0 + kc * 32 + c8 * 8, base + s * 8);
    }
  };

  STAGE_QK(0, 0, 0);
  wait_barrier();
  int cur = 0;

  for (int jt = 0; jt < 8; ++jt) {
    f32x4 sacc[4][4];
#pragma unroll
    for (int i = 0; i < 4; ++i)
#pragma unroll
      for (int j = 0; j < 4; ++j) sacc[i][j] = (f32x4)0.0f;

    // ---- S = Q K^T over d (8 chunks of 32), pipelined ----
    for (int kk = 0; kk < 8; ++kk) {
      if (kk < 7) STAGE_QK(jt, kk + 1, cur ^ 1);
      else        STAGE_V(jt, 0, cur ^ 1);
      const f32x4* q4 = (const f32x4*)(ldsS + cur * 8192);
      const f32x4* k4 = q4 + 512;
      bf16x8 aq[4], bk[4];
#pragma unroll
      for (int mi = 0; mi < 4; ++mi) {
        int row = rg * 64 + mi * 16 + lr;
        aq[mi] = __builtin_bit_cast(
            bf16x8, q4[((row >> 4) << 6) + (lq << 4) + (row & 15)]);
      }
#pragma unroll
      for (int ni = 0; ni < 4; ++ni) {
        int col = cg * 64 + ni * 16 + lr;
        bk[ni] = __builtin_bit_cast(
            bf16x8, k4[((col >> 4) << 6) + (lq << 4) + (col & 15)]);
      }
      __builtin_amdgcn_s_setprio(1);
#pragma unroll
      for (int mi = 0; mi < 4; ++mi)
#pragma unroll
        for (int ni = 0; ni < 4; ++ni)
          sacc[mi][ni] = MFMA(aq[mi], bk[ni], sacc[mi][ni]);
      __builtin_amdgcn_s_setprio(0);
      wait_barrier();
      cur ^= 1;
    }

    // ---- P = exp(S), row partial sums, P -> LDS (bf16) ----
    float prt[16];
#pragma unroll
    for (int i = 0; i < 16; ++i) prt[i] = 0.0f;
#pragma unroll
    for (int mi = 0; mi < 4; ++mi)
#pragma unroll
      for (int ni = 0; ni < 4; ++ni)
#pragma unroll
        for (int r = 0; r < 4; ++r) {
          float e = __expf(sacc[mi][ni][r]);
          prt[mi * 4 + r] += e;
          int m = rg * 64 + mi * 16 + lq * 4 + r;
          int jc = cg * 64 + ni * 16 + lr;
          ldsP[m * 136 + jc] = f2bf_rne(e);
        }
#pragma unroll
    for (int v = 0; v < 16; ++v) {
      float p = prt[v];
      p += __shfl_xor(p, 1, 64);
      p += __shfl_xor(p, 2, 64);
      p += __shfl_xor(p, 4, 64);
      p += __shfl_xor(p, 8, 64);
      lsum[v] += p;
    }
    __syncthreads();   // P visible to the sibling cg wave before PV reads

    // ---- O += P V (contraction over 128 keys, 4 chunks of 32), pipelined ----
    for (int kc = 0; kc < 4; ++kc) {
      if (kc < 3)      STAGE_V(jt, kc + 1, cur ^ 1);
      else if (jt < 7) STAGE_QK(jt + 1, 0, cur ^ 1);
      const f32x4* v4 = (const f32x4*)(ldsS + cur * 8192);
      const f32x4* p4 = (const f32x4*)ldsP;
      bf16x8 pf[4], vf[8];
#pragma unroll
      for (int mi = 0; mi < 4; ++mi) {
        int m = rg * 64 + mi * 16 + lr;
        pf[mi] = __builtin_bit_cast(bf16x8, p4[m * 17 + kc * 4 + lq]);
      }
#pragma unroll
      for (int ni = 0; ni < 8; ++ni) {
        int d = cg * 128 + ni * 16 + lr;
        vf[ni] = __builtin_bit_cast(
            bf16x8, v4[((d >> 4) << 6) + (lq << 4) + (d & 15)]);
      }
      __builtin_amdgcn_s_setprio(1);
#pragma unroll
      for (int mi = 0; mi < 4; ++mi)
#pragma unroll
        for (int ni = 0; ni < 8; ++ni)
          oacc[mi][ni] = MFMA(pf[mi], vf[ni], oacc[mi][ni]);
      __builtin_amdgcn_s_setprio(0);
      wait_barrier();
      cur ^= 1;
    }
  }

  // ---- epilogue: combine denominators across wave pairs, normalize ----
  float* lscr = (float*)ldsP;
  if (lr == 0) {
#pragma unroll
    for (int mi = 0; mi < 4; ++mi)
#pragma unroll
      for (int r = 0; r < 4; ++r)
        lscr[wid * 64 + mi * 16 + lq * 4 + r] = lsum[mi * 4 + r];
  }
  __syncthreads();
  float inv[16];
#pragma unroll
  for (int mi = 0; mi < 4; ++mi)
#pragma unroll
    for (int r = 0; r < 4; ++r) {
      float tot = lsum[mi * 4 + r] + lscr[(wid ^ 1) * 64 + mi * 16 + lq * 4 + r];
      inv[mi * 4 + r] = 1.0f / tot;
    }
#pragma unroll
  for (int mi = 0; mi < 4; ++mi)
#pragma unroll
    for (int ni = 0; ni < 8; ++ni)
#pragma unroll
      for (int r = 0; r < 4; ++r) {
        int i = i0 + rg * 64 + mi * 16 + lq * 4 + r;
        int d = cg * 128 + ni * 16 + lr;
        out[bq + (size_t)i * 256 + d] = oacc[mi][ni][r] * inv[mi * 4 + r];
      }
}

// ---------------------------------------------------------------------------
extern "C" void kernel_launch(void* const* d_in, const int* in_sizes, int n_in,
                              void* d_out, int out_size, void* d_ws,
                              size_t ws_size, hipStream_t stream) {
  (void)in_sizes; (void)n_in; (void)out_size; (void)ws_size;
  const float* q  = (const float*)d_in[0];
  const float* k  = (const float*)d_in[1];
  const float* v  = (const float*)d_in[2];
  const float* wq = (const float*)d_in[3];
  const float* wk = (const float*)d_in[4];
  const float* wv = (const float*)d_in[5];
  float* out = (float*)d_out;

  // ws layout: qh | kh | vt, each 128*1024*256 bf16 (67.1 MB) -> 201.3 MB
  short* qh = (short*)d_ws;
  short* kh = qh + (size_t)33554432;
  short* vt = kh + (size_t)33554432;
  // W bf16 scratch (384 KB) lives at the head of d_out; d_out is only
  // written by attn_kernel's epilogue, which runs strictly after proj.
  short* wbf = (short*)d_out;

  wconv_kernel<<<dim3(64, 3), dim3(256), 0, stream>>>(wq, wk, wv, wbf);
  proj_kernel<<<dim3(1024, 3), dim3(256), 0, stream>>>(
      q, k, v, wbf, qh, kh, vt);
  attn_kernel<<<dim3(128, 8), dim3(256), 0, stream>>>(qh, kh, vt, out);
}

// Round 4
// 828.794 us; speedup vs baseline: 1.1506x; 1.0923x over previous
//
#include <hip/hip_runtime.h>
#include <stdint.h>

// ---------------------------------------------------------------------------
// FrameSoftAttention: out = softmax((q Wq^T)(k Wk^T)^T / 16) (v Wv^T)
// B=128, I=J=1024, D_IN=D_INNER=256, fp32 in/out, bf16 MFMA compute.
// v5 = v4 with 512-thread blocks (8 waves) in proj+attn: same tiles, same
//      LDS (64/67.5 KB -> 2 blocks/CU), but 16 waves/CU instead of 8.
//      Round-3 counters: occupancy 11.5%, Mfma 15.6%, hbm 19% -> latency-
//      bound with only 2 waves/SIMD; this doubles latency-hiding TLP.
// v4: no min-occupancy launch bound (v3's (256,2) spilled: 602MB writes).
// v3: proj mat==2 transposes in LDS before vt store.
// v2: double-buffered 2-phase pipeline (stage-next-before-compute, one
//     vmcnt(0)+s_barrier per chunk); proj reads X once; W pre-bf16.
// ---------------------------------------------------------------------------

typedef __attribute__((ext_vector_type(4))) float f32x4;
typedef __attribute__((ext_vector_type(8))) short bf16x8;
typedef __attribute__((ext_vector_type(4))) uint32_t u32x4;
typedef __attribute__((ext_vector_type(4))) short s16x4;

#define MFMA(a, b, c) __builtin_amdgcn_mfma_f32_16x16x32_bf16(a, b, c, 0, 0, 0)

typedef const __attribute__((address_space(1))) uint32_t* gas1_t;
typedef __attribute__((address_space(3))) uint32_t* las3_t;

__device__ __forceinline__ void async16(const void* g, void* l) {
  // 16B direct global->LDS; lands at wave-uniform base + lane*16.
  __builtin_amdgcn_global_load_lds((gas1_t)g, (las3_t)l, 16, 0, 0);
}

__device__ __forceinline__ short f2bf_rne(float f) {
  uint32_t u = __builtin_bit_cast(uint32_t, f);
  u += 0x7FFFu + ((u >> 16) & 1u);
  return (short)(u >> 16);
}

// two fp32 -> packed bf16 pair by truncation (cheap; bias inside 2% budget)
__device__ __forceinline__ uint32_t pack2(float lo, float hi) {
  uint32_t a = __builtin_bit_cast(uint32_t, lo);
  uint32_t b = __builtin_bit_cast(uint32_t, hi);
  return (a >> 16) | (b & 0xFFFF0000u);
}

// Pipeline barrier: drain OWN in-flight global_load_lds, then block barrier.
__device__ __forceinline__ void wait_barrier() {
  __builtin_amdgcn_sched_barrier(0);
  asm volatile("s_waitcnt vmcnt(0)" ::: "memory");
  __builtin_amdgcn_s_barrier();
  __builtin_amdgcn_sched_barrier(0);
}

// ---------------------------------------------------------------------------
// W fp32 [256][256] -> bf16 row-major, all three mats. 768KB read, ~5us.
// ---------------------------------------------------------------------------
__global__ __launch_bounds__(256)
void wconv_kernel(const float* __restrict__ wq, const float* __restrict__ wk,
                  const float* __restrict__ wv, short* __restrict__ wbf) {
  const int mat = blockIdx.y;
  const float* w = (mat == 0) ? wq : (mat == 1) ? wk : wv;
  const int i = (blockIdx.x * 256 + threadIdx.x) * 4;
  f32x4 v = *(const f32x4*)(w + i);
  s16x4 o = {f2bf_rne(v.x), f2bf_rne(v.y), f2bf_rne(v.z), f2bf_rne(v.w)};
  *(s16x4*)(wbf + (size_t)mat * 65536 + i) = o;
}

// ---------------------------------------------------------------------------
// Projection: Y[m,e] = sum_d X[m,d] * W[e,d]; M=131072, N=K=256.
// One block = 128 rows x FULL 256 cols (X read once from HBM), 512 threads.
// 8 waves at 64x64 (acc[4][4]). K-loop: 8 chunks of 32, pipelined:
// half h (32KB) = X chunk 128x32 fp32 (16KB) | W chunk 256x32 bf16 (16KB).
// ---------------------------------------------------------------------------
__global__ __launch_bounds__(512)
void proj_kernel(const float* __restrict__ xq, const float* __restrict__ xk,
                 const float* __restrict__ xv, const short* __restrict__ wbf,
                 short* __restrict__ qh, short* __restrict__ kh,
                 short* __restrict__ vt) {
  __shared__ __align__(16) char smem[65536];   // 2 x 32KB halves
  short* ldst = (short*)smem;                  // epilogue alias [128][136]

  const int mat = blockIdx.y;
  const float* x = (mat == 0) ? xq : (mat == 1) ? xk : xv;
  const short* w = wbf + (size_t)mat * 65536;

  const int tile_m = blockIdx.x * 128;
  const int t = threadIdx.x;
  const int lane = t & 63, wid = t >> 6;        // wid in [0,8)
  const int wm = (wid & 1) * 64, wn = (wid >> 1) * 64;
  const int lr = lane & 15, lq = lane >> 4;

  f32x4 acc[4][4];
#pragma unroll
  for (int i = 0; i < 4; ++i)
#pragma unroll
    for (int j = 0; j < 4; ++j) acc[i][j] = (f32x4)0.0f;

  // stage chunk kk into half h: 4 async16 per thread (2 X + 2 W)
  auto STAGE = [&](int kk, int h) {
    char* base = smem + h * 32768;
    const int k0 = kk * 32;
#pragma unroll
    for (int c = 0; c < 2; ++c) {
      int s = c * 512 + t;
      // X slot(r,c8) = (r>>4)*128 + c8*16 + (r&15), c8 in 0..7 (fp32x4 units)
      int rx = ((s >> 7) << 4) | (s & 15);
      int cx = (s >> 4) & 7;
      async16(x + (size_t)(tile_m + rx) * 256 + k0 + cx * 4, base + s * 16);
      // W slot(r,c8) = (r>>4)*64 + c8*16 + (r&15), c8 in 0..3 (bf16x8 units)
      int rw = ((s >> 6) << 4) | (s & 15);
      int cw = (s >> 4) & 3;
      async16(w + (size_t)rw * 256 + k0 + cw * 8, base + 16384 + s * 16);
    }
  };

  STAGE(0, 0);
  wait_barrier();
  int cur = 0;
  for (int kk = 0; kk < 8; ++kk) {
    if (kk < 7) STAGE(kk + 1, cur ^ 1);   // loads fly under this chunk's work
    const f32x4* x4 = (const f32x4*)(smem + cur * 32768);
    const f32x4* w4 = (const f32x4*)(smem + cur * 32768 + 16384);
    bf16x8 af[4], bf[4];
#pragma unroll
    for (int mi = 0; mi < 4; ++mi) {
      int row = wm + mi * 16 + lr;
      int sl = ((row >> 4) << 7) + (lq << 5) + (row & 15);
      f32x4 lo = x4[sl], hi = x4[sl + 16];
      u32x4 pk = {pack2(lo.x, lo.y), pack2(lo.z, lo.w), pack2(hi.x, hi.y),
                  pack2(hi.z, hi.w)};
      af[mi] = __builtin_bit_cast(bf16x8, pk);
    }
#pragma unroll
    for (int ni = 0; ni < 4; ++ni) {
      int col = wn + ni * 16 + lr;
      bf[ni] = __builtin_bit_cast(
          bf16x8, w4[((col >> 4) << 6) + (lq << 4) + (col & 15)]);
    }
    __builtin_amdgcn_s_setprio(1);
#pragma unroll
    for (int mi = 0; mi < 4; ++mi)
#pragma unroll
      for (int ni = 0; ni < 4; ++ni)
        acc[mi][ni] = MFMA(af[mi], bf[ni], acc[mi][ni]);
    __builtin_amdgcn_s_setprio(0);
    wait_barrier();
    cur ^= 1;
  }

  // Epilogue: two 128-col passes through LDS -> coalesced 16B stores.
  // Pass p is written by the 4 waves with (wid>>1)>>1 == p.
  // mat==2 (V): transpose in LDS (ldst[n][m]) so LDS rows are e-rows,
  // matching the vt[e][j] store layout.
  const float scale = (mat == 0) ? 0.0625f : 1.0f;
  const int bb = tile_m >> 10, j0 = tile_m & 1023;
#pragma unroll
  for (int p = 0; p < 2; ++p) {
    if (((wid >> 1) >> 1) == p) {
#pragma unroll
      for (int mi = 0; mi < 4; ++mi)
#pragma unroll
        for (int ni = 0; ni < 4; ++ni)
#pragma unroll
          for (int r = 0; r < 4; ++r) {
            int m = wm + mi * 16 + lq * 4 + r;           // C/D row
            int n = ((wid >> 1) & 1) * 64 + ni * 16 + lr; // col local to pass
            short bv = f2bf_rne(acc[mi][ni][r] * scale);
            if (mat < 2) ldst[m * 136 + n] = bv;
            else         ldst[n * 136 + m] = bv;
          }
    }
    __syncthreads();
#pragma unroll
    for (int q = 0; q < 4; ++q) {
      int idx = q * 512 + t;
      int row = idx >> 4;
      int col8 = (idx & 15) * 8;
      bf16x8 vdat = *(const bf16x8*)(ldst + row * 136 + col8);
      short* dst;
      if (mat < 2) {
        short* o = (mat == 0) ? qh : kh;
        dst = o + (size_t)(tile_m + row) * 256 + p * 128 + col8;
      } else {
        dst = vt + ((size_t)(bb * 256 + p * 128 + row)) * 1024 + j0 + col8;
      }
      *(bf16x8*)dst = vdat;
    }
    __syncthreads();
  }
}

// ---------------------------------------------------------------------------
// Attention: one block per (batch, 128-row q tile), 512 threads (8 waves).
// grid=(128, 8) so all q-tiles of batch b hash to XCD b%8 (kh/vt L2 reuse).
// Wave (rg,cg): rg=wid>>1 owns rows rg*32; cg=wid&1 owns QK cols cg*64 /
// PV d-cols cg*128. Unit ring per j-tile: 8 QK chunks + 4 V chunks,
// double-buffered halves, one vmcnt(0)+s_barrier per unit.
// ---------------------------------------------------------------------------
__global__ __launch_bounds__(512)
void attn_kernel(const short* __restrict__ qh, const short* __restrict__ kh,
                 const short* __restrict__ vt, float* __restrict__ out) {
  __shared__ __align__(16) char smem[32768 + 34816];
  short* ldsS = (short*)smem;             // 2 x 16KB staging halves
  short* ldsP = (short*)(smem + 32768);   // P [128][136] bf16

  const int b = blockIdx.x;
  const int i0 = blockIdx.y * 128;
  const int t = threadIdx.x;
  const int lane = t & 63, wid = t >> 6;  // wid in [0,8)
  const int rg = wid >> 1, cg = wid & 1;  // rows rg*32, cols cg*64/128
  const int lr = lane & 15, lq = lane >> 4;
  const size_t bq = (size_t)b * 262144;

  f32x4 oacc[2][8];
#pragma unroll
  for (int i = 0; i < 2; ++i)
#pragma unroll
    for (int j = 0; j < 8; ++j) oacc[i][j] = (f32x4)0.0f;
  float lsum[8];
#pragma unroll
  for (int i = 0; i < 8; ++i) lsum[i] = 0.0f;

  // QK unit (jt,kk) -> half h: Q chunk 8KB | K chunk 8KB; 2 loads/thread
  auto STAGE_QK = [&](int jt, int kk, int h) {
    short* base = ldsS + h * 8192;
    const int j0 = jt * 128, k0 = kk * 32;
    int s = t;                             // 512 slots each
    int r = ((s >> 6) << 4) | (s & 15);
    int c8 = (s >> 4) & 3;
    async16(qh + bq + (size_t)(i0 + r) * 256 + k0 + c8 * 8, base + s * 8);
    async16(kh + bq + (size_t)(j0 + r) * 256 + k0 + c8 * 8, base + 4096 + s * 8);
  };
  // V unit (jt,kc) -> half h: vt 256 d-rows x 32 j (16KB); 2 loads/thread
  auto STAGE_V = [&](int jt, int kc, int h) {
    short* base = ldsS + h * 8192;
    const int j0 = jt * 128;
#pragma unroll
    for (int c = 0; c < 2; ++c) {
      int s = c * 512 + t;
      int d = ((s >> 6) << 4) | (s & 15);
      int c8 = (s >> 4) & 3;
      async16(vt + bq + (size_t)d * 1024 + j0 + kc * 32 + c8 * 8, base + s * 8);
    }
  };

  STAGE_QK(0, 0, 0);
  wait_barrier();
  int cur = 0;

  for (int jt = 0; jt < 8; ++jt) {
    f32x4 sacc[2][4];
#pragma unroll
    for (int i = 0; i < 2; ++i)
#pragma unroll
      for (int j = 0; j < 4; ++j) sacc[i][j] = (f32x4)0.0f;

    // ---- S = Q K^T over d (8 chunks of 32), pipelined ----
    for (int kk = 0; kk < 8; ++kk) {
      if (kk < 7) STAGE_QK(jt, kk + 1, cur ^ 1);
      else        STAGE_V(jt, 0, cur ^ 1);
      const f32x4* q4 = (const f32x4*)(ldsS + cur * 8192);
      const f32x4* k4 = q4 + 512;
      bf16x8 aq[2], bk[4];
#pragma unroll
      for (int mi = 0; mi < 2; ++mi) {
        int row = rg * 32 + mi * 16 + lr;
        aq[mi] = __builtin_bit_cast(
            bf16x8, q4[((row >> 4) << 6) + (lq << 4) + (row & 15)]);
      }
#pragma unroll
      for (int ni = 0; ni < 4; ++ni) {
        int col = cg * 64 + ni * 16 + lr;
        bk[ni] = __builtin_bit_cast(
            bf16x8, k4[((col >> 4) << 6) + (lq << 4) + (col & 15)]);
      }
      __builtin_amdgcn_s_setprio(1);
#pragma unroll
      for (int mi = 0; mi < 2; ++mi)
#pragma unroll
        for (int ni = 0; ni < 4; ++ni)
          sacc[mi][ni] = MFMA(aq[mi], bk[ni], sacc[mi][ni]);
      __builtin_amdgcn_s_setprio(0);
      wait_barrier();
      cur ^= 1;
    }

    // ---- P = exp(S), row partial sums, P -> LDS (bf16) ----
    float prt[8];
#pragma unroll
    for (int i = 0; i < 8; ++i) prt[i] = 0.0f;
#pragma unroll
    for (int mi = 0; mi < 2; ++mi)
#pragma unroll
      for (int ni = 0; ni < 4; ++ni)
#pragma unroll
        for (int r = 0; r < 4; ++r) {
          float e = __expf(sacc[mi][ni][r]);
          prt[mi * 4 + r] += e;
          int m = rg * 32 + mi * 16 + lq * 4 + r;
          int jc = cg * 64 + ni * 16 + lr;
          ldsP[m * 136 + jc] = f2bf_rne(e);
        }
#pragma unroll
    for (int v = 0; v < 8; ++v) {
      float p = prt[v];
      p += __shfl_xor(p, 1, 64);
      p += __shfl_xor(p, 2, 64);
      p += __shfl_xor(p, 4, 64);
      p += __shfl_xor(p, 8, 64);
      lsum[v] += p;
    }
    __syncthreads();   // P visible to the sibling cg wave before PV reads

    // ---- O += P V (contraction over 128 keys, 4 chunks of 32), pipelined ----
    for (int kc = 0; kc < 4; ++kc) {
      if (kc < 3)      STAGE_V(jt, kc + 1, cur ^ 1);
      else if (jt < 7) STAGE_QK(jt + 1, 0, cur ^ 1);
      const f32x4* v4 = (const f32x4*)(ldsS + cur * 8192);
      const f32x4* p4 = (const f32x4*)ldsP;
      bf16x8 pf[2], vf[8];
#pragma unroll
      for (int mi = 0; mi < 2; ++mi) {
        int m = rg * 32 + mi * 16 + lr;
        pf[mi] = __builtin_bit_cast(bf16x8, p4[m * 17 + kc * 4 + lq]);
      }
#pragma unroll
      for (int ni = 0; ni < 8; ++ni) {
        int d = cg * 128 + ni * 16 + lr;
        vf[ni] = __builtin_bit_cast(
            bf16x8, v4[((d >> 4) << 6) + (lq << 4) + (d & 15)]);
      }
      __builtin_amdgcn_s_setprio(1);
#pragma unroll
      for (int mi = 0; mi < 2; ++mi)
#pragma unroll
        for (int ni = 0; ni < 8; ++ni)
          oacc[mi][ni] = MFMA(pf[mi], vf[ni], oacc[mi][ni]);
      __builtin_amdgcn_s_setprio(0);
      wait_barrier();
      cur ^= 1;
    }
  }

  // ---- epilogue: combine denominators across wave pairs, normalize ----
  float* lscr = (float*)ldsP;
  if (lr == 0) {
#pragma unroll
    for (int mi = 0; mi < 2; ++mi)
#pragma unroll
      for (int r = 0; r < 4; ++r)
        lscr[wid * 32 + mi * 16 + lq * 4 + r] = lsum[mi * 4 + r];
  }
  __syncthreads();
  float inv[8];
#pragma unroll
  for (int mi = 0; mi < 2; ++mi)
#pragma unroll
    for (int r = 0; r < 4; ++r) {
      float tot = lsum[mi * 4 + r] + lscr[(wid ^ 1) * 32 + mi * 16 + lq * 4 + r];
      inv[mi * 4 + r] = 1.0f / tot;
    }
#pragma unroll
  for (int mi = 0; mi < 2; ++mi)
#pragma unroll
    for (int ni = 0; ni < 8; ++ni)
#pragma unroll
      for (int r = 0; r < 4; ++r) {
        int i = i0 + rg * 32 + mi * 16 + lq * 4 + r;
        int d = cg * 128 + ni * 16 + lr;
        out[bq + (size_t)i * 256 + d] = oacc[mi][ni][r] * inv[mi * 4 + r];
      }
}

// ---------------------------------------------------------------------------
extern "C" void kernel_launch(void* const* d_in, const int* in_sizes, int n_in,
                              void* d_out, int out_size, void* d_ws,
                              size_t ws_size, hipStream_t stream) {
  (void)in_sizes; (void)n_in; (void)out_size; (void)ws_size;
  const float* q  = (const float*)d_in[0];
  const float* k  = (const float*)d_in[1];
  const float* v  = (const float*)d_in[2];
  const float* wq = (const float*)d_in[3];
  const float* wk = (const float*)d_in[4];
  const float* wv = (const float*)d_in[5];
  float* out = (float*)d_out;

  // ws layout: qh | kh | vt, each 128*1024*256 bf16 (67.1 MB) -> 201.3 MB
  short* qh = (short*)d_ws;
  short* kh = qh + (size_t)33554432;
  short* vt = kh + (size_t)33554432;
  // W bf16 scratch (384 KB) lives at the head of d_out; d_out is only
  // written by attn_kernel's epilogue, which runs strictly after proj.
  short* wbf = (short*)d_out;

  wconv_kernel<<<dim3(64, 3), dim3(256), 0, stream>>>(wq, wk, wv, wbf);
  proj_kernel<<<dim3(1024, 3), dim3(512), 0, stream>>>(
      q, k, v, wbf, qh, kh, vt);
  attn_kernel<<<dim3(128, 8), dim3(512), 0, stream>>>(qh, kh, vt, out);
}

// Round 5
// 738.639 us; speedup vs baseline: 1.2910x; 1.1221x over previous
//
#include <hip/hip_runtime.h>
#include <stdint.h>

// ---------------------------------------------------------------------------
// FrameSoftAttention: out = softmax((q Wq^T)(k Wk^T)^T / 16) (v Wv^T)
// B=128, I=J=1024, D_IN=D_INNER=256, fp32 in/out, bf16 MFMA compute.
// v6: depth-2 counted-vmcnt staging ring (T4), constant LDS:
//     attn: 4-ring of 8KB units (Q_kk / K_kk / V-lo / V-hi, 1 load/thread),
//           vmcnt(1) per unit -> loads span 2 units; P-sync via lgkmcnt(0)+
//           raw s_barrier (keeps ring loads alive).
//     proj: 4-ring of 16KB units (X_kk / W_kk, 2 loads/thread), vmcnt(2).
//     Round-4 evidence: occupancy doubled (23%) but dur -5% only -> not
//     TLP-bound; per-unit vmcnt(0) drain was the floor.
// v5: 512-thread blocks. v4: no min-occupancy bound (spill!). v3: V
//     transpose-in-LDS. v2: stage-before-compute pipeline, X read once.
// ---------------------------------------------------------------------------

typedef __attribute__((ext_vector_type(4))) float f32x4;
typedef __attribute__((ext_vector_type(8))) short bf16x8;
typedef __attribute__((ext_vector_type(4))) uint32_t u32x4;
typedef __attribute__((ext_vector_type(4))) short s16x4;

#define MFMA(a, b, c) __builtin_amdgcn_mfma_f32_16x16x32_bf16(a, b, c, 0, 0, 0)

typedef const __attribute__((address_space(1))) uint32_t* gas1_t;
typedef __attribute__((address_space(3))) uint32_t* las3_t;

__device__ __forceinline__ void async16(const void* g, void* l) {
  // 16B direct global->LDS; lands at wave-uniform base + lane*16.
  __builtin_amdgcn_global_load_lds((gas1_t)g, (las3_t)l, 16, 0, 0);
}

__device__ __forceinline__ short f2bf_rne(float f) {
  uint32_t u = __builtin_bit_cast(uint32_t, f);
  u += 0x7FFFu + ((u >> 16) & 1u);
  return (short)(u >> 16);
}

// two fp32 -> packed bf16 pair by truncation (cheap; bias inside 2% budget)
__device__ __forceinline__ uint32_t pack2(float lo, float hi) {
  uint32_t a = __builtin_bit_cast(uint32_t, lo);
  uint32_t b = __builtin_bit_cast(uint32_t, hi);
  return (a >> 16) | (b & 0xFFFF0000u);
}

// Counted-vmcnt unit barrier: wait until <=N of this wave's global_load_lds
// remain in flight (N = loads/thread of ONE in-flight unit; 0 at tail),
// then block barrier. Loads for the next unit stay in flight across it.
template <int N>
__device__ __forceinline__ void unit_wait() {
  __builtin_amdgcn_sched_barrier(0);
  if constexpr (N == 0)
    asm volatile("s_waitcnt vmcnt(0)" ::: "memory");
  else if constexpr (N == 1)
    asm volatile("s_waitcnt vmcnt(1)" ::: "memory");
  else
    asm volatile("s_waitcnt vmcnt(2)" ::: "memory");
  __builtin_amdgcn_s_barrier();
  __builtin_amdgcn_sched_barrier(0);
}

// ---------------------------------------------------------------------------
// W fp32 [256][256] -> bf16 row-major, all three mats. 768KB read, ~5us.
// ---------------------------------------------------------------------------
__global__ __launch_bounds__(256)
void wconv_kernel(const float* __restrict__ wq, const float* __restrict__ wk,
                  const float* __restrict__ wv, short* __restrict__ wbf) {
  const int mat = blockIdx.y;
  const float* w = (mat == 0) ? wq : (mat == 1) ? wk : wv;
  const int i = (blockIdx.x * 256 + threadIdx.x) * 4;
  f32x4 v = *(const f32x4*)(w + i);
  s16x4 o = {f2bf_rne(v.x), f2bf_rne(v.y), f2bf_rne(v.z), f2bf_rne(v.w)};
  *(s16x4*)(wbf + (size_t)mat * 65536 + i) = o;
}

// ---------------------------------------------------------------------------
// Projection: Y[m,e] = sum_d X[m,d] * W[e,d]; M=131072, N=K=256.
// One block = 128 rows x FULL 256 cols (X read once from HBM), 512 threads.
// 8 waves at 64x64 (acc[4][4]). K-loop: 16 units (X_kk, W_kk alternating),
// 4-ring of 16KB, vmcnt(2) depth-2 pipeline. Compute on W units.
// ---------------------------------------------------------------------------
__global__ __launch_bounds__(512)
void proj_kernel(const float* __restrict__ xq, const float* __restrict__ xk,
                 const float* __restrict__ xv, const short* __restrict__ wbf,
                 short* __restrict__ qh, short* __restrict__ kh,
                 short* __restrict__ vt) {
  __shared__ __align__(16) char smem[65536];   // 4 x 16KB ring
  short* ldst = (short*)smem;                  // epilogue alias [128][136]

  const int mat = blockIdx.y;
  const float* x = (mat == 0) ? xq : (mat == 1) ? xk : xv;
  const short* w = wbf + (size_t)mat * 65536;

  const int tile_m = blockIdx.x * 128;
  const int t = threadIdx.x;
  const int lane = t & 63, wid = t >> 6;        // wid in [0,8)
  const int wm = (wid & 1) * 64, wn = (wid >> 1) * 64;
  const int lr = lane & 15, lq = lane >> 4;

  f32x4 acc[4][4];
#pragma unroll
  for (int i = 0; i < 4; ++i)
#pragma unroll
    for (int j = 0; j < 4; ++j) acc[i][j] = (f32x4)0.0f;

  // unit u (0..15): even = X chunk kk=u/2 (128x32 fp32), odd = W chunk
  // (256x32 bf16). Each 16KB, 2 loads/thread, into ring slot u&3.
  auto ISSUE = [&](int u) {
    if (u >= 16) return;
    char* base = smem + (u & 3) * 16384;
    const int k0 = (u >> 1) * 32;
    if ((u & 1) == 0) {
#pragma unroll
      for (int c = 0; c < 2; ++c) {
        int s = c * 512 + t;
        // X slot(r,c8) = (r>>4)*128 + c8*16 + (r&15), c8 in 0..7 (f32x4)
        int rx = ((s >> 7) << 4) | (s & 15);
        int cx = (s >> 4) & 7;
        async16(x + (size_t)(tile_m + rx) * 256 + k0 + cx * 4, base + s * 16);
      }
    } else {
#pragma unroll
      for (int c = 0; c < 2; ++c) {
        int s = c * 512 + t;
        // W slot(r,c8) = (r>>4)*64 + c8*16 + (r&15), c8 in 0..3 (bf16x8)
        int rw = ((s >> 6) << 4) | (s & 15);
        int cw = (s >> 4) & 3;
        async16(w + (size_t)rw * 256 + k0 + cw * 8, base + s * 16);
      }
    }
  };

  ISSUE(0);
  ISSUE(1);
  for (int kk = 0; kk < 8; ++kk) {
    const int u = kk * 2 + 1;                 // W unit index of this chunk
    // X unit (u-1)
    unit_wait<2>();
    ISSUE(u + 1);
    // W unit (u)
    if (kk == 7) unit_wait<0>(); else unit_wait<2>();
    ISSUE(u + 2);
    const f32x4* x4 = (const f32x4*)(smem + ((u - 1) & 3) * 16384);
    const f32x4* w4 = (const f32x4*)(smem + (u & 3) * 16384);
    bf16x8 af[4], bf[4];
#pragma unroll
    for (int mi = 0; mi < 4; ++mi) {
      int row = wm + mi * 16 + lr;
      int sl = ((row >> 4) << 7) + (lq << 5) + (row & 15);
      f32x4 lo = x4[sl], hi = x4[sl + 16];
      u32x4 pk = {pack2(lo.x, lo.y), pack2(lo.z, lo.w), pack2(hi.x, hi.y),
                  pack2(hi.z, hi.w)};
      af[mi] = __builtin_bit_cast(bf16x8, pk);
    }
#pragma unroll
    for (int ni = 0; ni < 4; ++ni) {
      int col = wn + ni * 16 + lr;
      bf[ni] = __builtin_bit_cast(
          bf16x8, w4[((col >> 4) << 6) + (lq << 4) + (col & 15)]);
    }
    __builtin_amdgcn_s_setprio(1);
#pragma unroll
    for (int mi = 0; mi < 4; ++mi)
#pragma unroll
      for (int ni = 0; ni < 4; ++ni)
        acc[mi][ni] = MFMA(af[mi], bf[ni], acc[mi][ni]);
    __builtin_amdgcn_s_setprio(0);
  }
  __syncthreads();   // all waves done computing before ldst aliases the ring

  // Epilogue: two 128-col passes through LDS -> coalesced 16B stores.
  // mat==2 (V): transpose in LDS (ldst[n][m]) so LDS rows are e-rows,
  // matching the vt[e][j] store layout.
  const float scale = (mat == 0) ? 0.0625f : 1.0f;
  const int bb = tile_m >> 10, j0 = tile_m & 1023;
#pragma unroll
  for (int p = 0; p < 2; ++p) {
    if (((wid >> 1) >> 1) == p) {
#pragma unroll
      for (int mi = 0; mi < 4; ++mi)
#pragma unroll
        for (int ni = 0; ni < 4; ++ni)
#pragma unroll
          for (int r = 0; r < 4; ++r) {
            int m = wm + mi * 16 + lq * 4 + r;            // C/D row
            int n = ((wid >> 1) & 1) * 64 + ni * 16 + lr; // col local to pass
            short bv = f2bf_rne(acc[mi][ni][r] * scale);
            if (mat < 2) ldst[m * 136 + n] = bv;
            else         ldst[n * 136 + m] = bv;
          }
    }
    __syncthreads();
#pragma unroll
    for (int q = 0; q < 4; ++q) {
      int idx = q * 512 + t;
      int row = idx >> 4;
      int col8 = (idx & 15) * 8;
      bf16x8 vdat = *(const bf16x8*)(ldst + row * 136 + col8);
      short* dst;
      if (mat < 2) {
        short* o = (mat == 0) ? qh : kh;
        dst = o + (size_t)(tile_m + row) * 256 + p * 128 + col8;
      } else {
        dst = vt + ((size_t)(bb * 256 + p * 128 + row)) * 1024 + j0 + col8;
      }
      *(bf16x8*)dst = vdat;
    }
    __syncthreads();
  }
}

// ---------------------------------------------------------------------------
// Attention: one block per (batch, 128-row q tile), 512 threads (8 waves).
// grid=(128, 8) so all q-tiles of batch b hash to XCD b%8 (kh/vt L2 reuse).
// Unit stream per j-tile (24 x 8KB units, 1 load/thread each):
//   Q0 K0 Q1 K1 ... Q7 K7 | Vlo0 Vhi0 ... Vlo3 Vhi3
// 4-ring of 8KB, vmcnt(1) depth-2; compute on K units (QK MFMA) and Vhi
// units (PV MFMA). P-sync via lgkmcnt(0) + raw s_barrier (next unit's).
// ---------------------------------------------------------------------------
__global__ __launch_bounds__(512)
void attn_kernel(const short* __restrict__ qh, const short* __restrict__ kh,
                 const short* __restrict__ vt, float* __restrict__ out) {
  __shared__ __align__(16) char smem[32768 + 34816];
  short* ldsS = (short*)smem;             // 4 x 8KB (4096-short) ring
  short* ldsP = (short*)(smem + 32768);   // P [128][136] bf16

  const int b = blockIdx.x;
  const int i0 = blockIdx.y * 128;
  const int t = threadIdx.x;
  const int lane = t & 63, wid = t >> 6;  // wid in [0,8)
  const int rg = wid >> 1, cg = wid & 1;  // rows rg*32, cols cg*64/128
  const int lr = lane & 15, lq = lane >> 4;
  const size_t bq = (size_t)b * 262144;

  f32x4 oacc[2][8];
#pragma unroll
  for (int i = 0; i < 2; ++i)
#pragma unroll
    for (int j = 0; j < 8; ++j) oacc[i][j] = (f32x4)0.0f;
  float lsum[8];
#pragma unroll
  for (int i = 0; i < 8; ++i) lsum[i] = 0.0f;

  // unit u (0..191): jt = u/24, r = u%24.
  //  r<16: kk=r>>1; even r = Q chunk (i0 rows, k0=kk*32), odd = K chunk.
  //  r>=16: v=r-16; kc=v>>1; half=v&1: vt d-rows [half*128,+128), 32 keys.
  auto ISSUE = [&](int u) {
    if (u >= 192) return;
    short* base = ldsS + (u & 3) * 4096;
    const int jt = u / 24, r = u % 24;
    const int j0 = jt * 128;
    const int s = t;                       // 512 slots of 16B = 8KB
    if (r < 16) {
      const int k0 = (r >> 1) * 32;
      int rr = ((s >> 6) << 4) | (s & 15);
      int c8 = (s >> 4) & 3;
      if ((r & 1) == 0)
        async16(qh + bq + (size_t)(i0 + rr) * 256 + k0 + c8 * 8, base + s * 8);
      else
        async16(kh + bq + (size_t)(j0 + rr) * 256 + k0 + c8 * 8, base + s * 8);
    } else {
      const int v = r - 16;
      const int kc = v >> 1, half = v & 1;
      int d = (half << 7) | ((s >> 6) << 4) | (s & 15);
      int c8 = (s >> 4) & 3;
      async16(vt + bq + (size_t)d * 1024 + j0 + kc * 32 + c8 * 8, base + s * 8);
    }
  };

  ISSUE(0);
  ISSUE(1);
  int u = 0;

  for (int jt = 0; jt < 8; ++jt) {
    f32x4 sacc[2][4];
#pragma unroll
    for (int i = 0; i < 2; ++i)
#pragma unroll
      for (int j = 0; j < 4; ++j) sacc[i][j] = (f32x4)0.0f;

    // ---- S = Q K^T over d (8 chunks of 32), Q/K units alternating ----
    for (int kk = 0; kk < 8; ++kk) {
      unit_wait<1>();                      // Q unit u landed
      ISSUE(u + 2);
      ++u;
      unit_wait<1>();                      // K unit u landed
      ISSUE(u + 2);
      const f32x4* q4 = (const f32x4*)(ldsS + ((u - 1) & 3) * 4096);
      const f32x4* k4 = (const f32x4*)(ldsS + (u & 3) * 4096);
      bf16x8 aq[2], bk[4];
#pragma unroll
      for (int mi = 0; mi < 2; ++mi) {
        int row = rg * 32 + mi * 16 + lr;
        aq[mi] = __builtin_bit_cast(
            bf16x8, q4[((row >> 4) << 6) + (lq << 4) + (row & 15)]);
      }
#pragma unroll
      for (int ni = 0; ni < 4; ++ni) {
        int col = cg * 64 + ni * 16 + lr;
        bk[ni] = __builtin_bit_cast(
            bf16x8, k4[((col >> 4) << 6) + (lq << 4) + (col & 15)]);
      }
      __builtin_amdgcn_s_setprio(1);
#pragma unroll
      for (int mi = 0; mi < 2; ++mi)
#pragma unroll
        for (int ni = 0; ni < 4; ++ni)
          sacc[mi][ni] = MFMA(aq[mi], bk[ni], sacc[mi][ni]);
      __builtin_amdgcn_s_setprio(0);
      ++u;
    }

    // ---- P = exp(S), row partial sums, P -> LDS (bf16) ----
    float prt[8];
#pragma unroll
    for (int i = 0; i < 8; ++i) prt[i] = 0.0f;
#pragma unroll
    for (int mi = 0; mi < 2; ++mi)
#pragma unroll
      for (int ni = 0; ni < 4; ++ni)
#pragma unroll
        for (int r = 0; r < 4; ++r) {
          float e = __expf(sacc[mi][ni][r]);
          prt[mi * 4 + r] += e;
          int m = rg * 32 + mi * 16 + lq * 4 + r;
          int jc = cg * 64 + ni * 16 + lr;
          ldsP[m * 136 + jc] = f2bf_rne(e);
        }
#pragma unroll
    for (int v = 0; v < 8; ++v) {
      float p = prt[v];
      p += __shfl_xor(p, 1, 64);
      p += __shfl_xor(p, 2, 64);
      p += __shfl_xor(p, 4, 64);
      p += __shfl_xor(p, 8, 64);
      lsum[v] += p;
    }
    // P ds_writes retired here; the NEXT unit barrier (Vlo0) publishes them
    // to the sibling wave before the first PV read (at Vhi0, one later).
    asm volatile("s_waitcnt lgkmcnt(0)" ::: "memory");

    // ---- O += P V (4 kc chunks; Vlo/Vhi units) ----
    for (int kc = 0; kc < 4; ++kc) {
      unit_wait<1>();                      // Vlo unit u landed
      ISSUE(u + 2);
      ++u;
      if (jt == 7 && kc == 3) unit_wait<0>(); else unit_wait<1>();
      ISSUE(u + 2);
      // cg=0 waves read d 0..127 (Vlo, ring u-1); cg=1 read Vhi (ring u).
      const f32x4* v4 =
          (const f32x4*)(ldsS + ((cg ? u : (u - 1)) & 3) * 4096);
      const f32x4* p4 = (const f32x4*)ldsP;
      bf16x8 pf[2], vf[8];
#pragma unroll
      for (int mi = 0; mi < 2; ++mi) {
        int m = rg * 32 + mi * 16 + lr;
        pf[mi] = __builtin_bit_cast(bf16x8, p4[m * 17 + kc * 4 + lq]);
      }
#pragma unroll
      for (int ni = 0; ni < 8; ++ni) {
        // local d' = ni*16+lr (0..127) within the wave's half-unit
        vf[ni] = __builtin_bit_cast(bf16x8, v4[ni * 64 + (lq << 4) + lr]);
      }
      __builtin_amdgcn_s_setprio(1);
#pragma unroll
      for (int mi = 0; mi < 2; ++mi)
#pragma unroll
        for (int ni = 0; ni < 8; ++ni)
          oacc[mi][ni] = MFMA(pf[mi], vf[ni], oacc[mi][ni]);
      __builtin_amdgcn_s_setprio(0);
      ++u;
    }
  }
  __syncthreads();   // all PV reads of ldsP done before lscr aliases it

  // ---- epilogue: combine denominators across wave pairs, normalize ----
  float* lscr = (float*)ldsP;
  if (lr == 0) {
#pragma unroll
    for (int mi = 0; mi < 2; ++mi)
#pragma unroll
      for (int r = 0; r < 4; ++r)
        lscr[wid * 32 + mi * 16 + lq * 4 + r] = lsum[mi * 4 + r];
  }
  __syncthreads();
  float inv[8];
#pragma unroll
  for (int mi = 0; mi < 2; ++mi)
#pragma unroll
    for (int r = 0; r < 4; ++r) {
      float tot = lsum[mi * 4 + r] + lscr[(wid ^ 1) * 32 + mi * 16 + lq * 4 + r];
      inv[mi * 4 + r] = 1.0f / tot;
    }
#pragma unroll
  for (int mi = 0; mi < 2; ++mi)
#pragma unroll
    for (int ni = 0; ni < 8; ++ni)
#pragma unroll
      for (int r = 0; r < 4; ++r) {
        int i = i0 + rg * 32 + mi * 16 + lq * 4 + r;
        int d = cg * 128 + ni * 16 + lr;
        out[bq + (size_t)i * 256 + d] = oacc[mi][ni][r] * inv[mi * 4 + r];
      }
}

// ---------------------------------------------------------------------------
extern "C" void kernel_launch(void* const* d_in, const int* in_sizes, int n_in,
                              void* d_out, int out_size, void* d_ws,
                              size_t ws_size, hipStream_t stream) {
  (void)in_sizes; (void)n_in; (void)out_size; (void)ws_size;
  const float* q  = (const float*)d_in[0];
  const float* k  = (const float*)d_in[1];
  const float* v  = (const float*)d_in[2];
  const float* wq = (const float*)d_in[3];
  const float* wk = (const float*)d_in[4];
  const float* wv = (const float*)d_in[5];
  float* out = (float*)d_out;

  // ws layout: qh | kh | vt, each 128*1024*256 bf16 (67.1 MB) -> 201.3 MB
  short* qh = (short*)d_ws;
  short* kh = qh + (size_t)33554432;
  short* vt = kh + (size_t)33554432;
  // W bf16 scratch (384 KB) lives at the head of d_out; d_out is only
  // written by attn_kernel's epilogue, which runs strictly after proj.
  short* wbf = (short*)d_out;

  wconv_kernel<<<dim3(64, 3), dim3(256), 0, stream>>>(wq, wk, wv, wbf);
  proj_kernel<<<dim3(1024, 3), dim3(512), 0, stream>>>(
      q, k, v, wbf, qh, kh, vt);
  attn_kernel<<<dim3(128, 8), dim3(512), 0, stream>>>(qh, kh, vt, out);
}